// Round 1
// baseline (197.445 us; speedup 1.0000x reference)
//
#include <hip/hip_runtime.h>

// Problem dims (fixed by setup_inputs): x [B,N,C], adapter dim D, patch grid HxH
#define B_  64
#define N_  1024
#define H_  32
#define C_  768
#define D_  8

__device__ __forceinline__ float qgelu(float v) {
    // v * sigmoid(1.702 v) = v / (1 + exp(-1.702 v))
    return v / (1.0f + __expf(-1.702f * v));
}

// ---------------- Kernel 1: x_down = quick_gelu(x @ Wd + bd) ----------------
// One wave (64 lanes) per row of x. Each lane loads 3 float4 (768 floats/row
// across 64 lanes), accumulates 8 partial dots against Wd^T staged in LDS,
// then a 6-step butterfly reduce; lane 0 applies bias+gelu and stores 8 f32.
__global__ __launch_bounds__(256, 4) void k_down(
    const float* __restrict__ x, const float* __restrict__ Wd,
    const float* __restrict__ bd, float* __restrict__ t1, int nrows)
{
    __shared__ float sW[D_ * C_];   // transposed: sW[d*C_ + c] = Wd[c*D_ + d]
    __shared__ float sbd[D_];
    for (int i = threadIdx.x; i < D_ * C_; i += 256) {
        int d = i / C_, c = i - d * C_;
        sW[i] = Wd[c * D_ + d];
    }
    if (threadIdx.x < D_) sbd[threadIdx.x] = bd[threadIdx.x];
    __syncthreads();

    const int wid  = threadIdx.x >> 6;
    const int lane = threadIdx.x & 63;
    const int wstride = gridDim.x * 4;

    for (int row = blockIdx.x * 4 + wid; row < nrows; row += wstride) {
        const float4* xr = (const float4*)(x + (size_t)row * C_);
        float acc[D_];
#pragma unroll
        for (int d = 0; d < D_; ++d) acc[d] = 0.0f;

#pragma unroll
        for (int k = 0; k < (C_ / 4) / 64; ++k) {     // 3 iterations
            const int c4 = lane + k * 64;             // float4 index in row
            const float4 v = xr[c4];
#pragma unroll
            for (int d = 0; d < D_; ++d) {
                const float4 w = *(const float4*)&sW[d * C_ + c4 * 4];
                acc[d] += v.x * w.x + v.y * w.y + v.z * w.z + v.w * w.w;
            }
        }
        // full-wave butterfly reduce (all lanes end with the row sums)
#pragma unroll
        for (int off = 32; off >= 1; off >>= 1) {
#pragma unroll
            for (int d = 0; d < D_; ++d)
                acc[d] += __shfl_xor(acc[d], off, 64);
        }
        if (lane == 0) {
            float4 o0, o1;
            o0.x = qgelu(acc[0] + sbd[0]);
            o0.y = qgelu(acc[1] + sbd[1]);
            o0.z = qgelu(acc[2] + sbd[2]);
            o0.w = qgelu(acc[3] + sbd[3]);
            o1.x = qgelu(acc[4] + sbd[4]);
            o1.y = qgelu(acc[5] + sbd[5]);
            o1.z = qgelu(acc[6] + sbd[6]);
            o1.w = qgelu(acc[7] + sbd[7]);
            float* tp = t1 + (size_t)row * D_;
            *(float4*)tp       = o0;
            *(float4*)(tp + 4) = o1;
        }
    }
}

// ------------- Kernel 2: t2 = quick_gelu(conv3x3(t1) + bc) ------------------
// 4 blocks per image; each block computes an 8-row strip of the 32x32 grid.
// Strip + zero-padded halo (10 rows) staged in LDS. 1 pixel per thread.
__global__ __launch_bounds__(256, 4) void k_conv(
    const float* __restrict__ t1, const float* __restrict__ Wc,
    const float* __restrict__ bc, float* __restrict__ t2)
{
    __shared__ float sIn[10 * H_ * D_];     // 10 rows x 32 cols x 8 ch = 10 KB
    __shared__ float sWc[9 * D_ * D_];      // 2304 B, layout [kh][kw][ci][co]
    __shared__ float sbc[D_];

    const int img   = blockIdx.x >> 2;
    const int strip = blockIdx.x & 3;
    const int h0    = strip * 8;
    const float* in = t1 + (size_t)img * N_ * D_;

    // load 10 rows (h0-1 .. h0+8) with zero pad outside [0,32)
#pragma unroll
    for (int j = 0; j < 10; ++j) {
        const int i  = threadIdx.x + j * 256;   // i in [0, 2560)
        const int lr = i >> 8;                  // local row (32*8 = 256/row)
        const int rem = i & 255;
        const int g  = h0 - 1 + lr;
        sIn[i] = (g >= 0 && g < H_) ? in[(size_t)g * H_ * D_ + rem] : 0.0f;
    }
    for (int i = threadIdx.x; i < 9 * D_ * D_; i += 256) sWc[i] = Wc[i];
    if (threadIdx.x < D_) sbc[threadIdx.x] = bc[threadIdx.x];
    __syncthreads();

    const int lh = threadIdx.x >> 5;            // 0..7 strip row
    const int w  = threadIdx.x & 31;            // 0..31 col
    float acc[D_];
#pragma unroll
    for (int co = 0; co < D_; ++co) acc[co] = sbc[co];

#pragma unroll
    for (int kh = 0; kh < 3; ++kh) {
        const int lrow = lh + kh;               // rows are zero-padded in LDS
#pragma unroll
        for (int kw = 0; kw < 3; ++kw) {
            const int ww = w + kw - 1;
            if (ww < 0 || ww >= H_) continue;
            const float* ip = &sIn[(lrow * H_ + ww) * D_];
            const float* wp = &sWc[(kh * 3 + kw) * D_ * D_];
#pragma unroll
            for (int ci = 0; ci < D_; ++ci) {
                const float iv = ip[ci];
#pragma unroll
                for (int co = 0; co < D_; ++co)
                    acc[co] += iv * wp[ci * D_ + co];
            }
        }
    }
    float4 o0, o1;
    o0.x = qgelu(acc[0]); o0.y = qgelu(acc[1]);
    o0.z = qgelu(acc[2]); o0.w = qgelu(acc[3]);
    o1.x = qgelu(acc[4]); o1.y = qgelu(acc[5]);
    o1.z = qgelu(acc[6]); o1.w = qgelu(acc[7]);
    float* tp = t2 + ((size_t)img * N_ + (size_t)(h0 + lh) * H_ + w) * D_;
    *(float4*)tp       = o0;
    *(float4*)(tp + 4) = o1;
}

// ---------------- Kernel 3: out = t2 @ Wu + bu ------------------------------
// Wu is [D][C] row-major already. Stage it (24 KB) + bu in LDS. Each block
// iteration covers 4 rows; 4 rows x 192 float4 = 768 tasks = 256 thr x 3.
__global__ __launch_bounds__(256, 4) void k_up(
    const float* __restrict__ t2, const float* __restrict__ Wu,
    const float* __restrict__ bu, float* __restrict__ out, int nrows)
{
    __shared__ float sW[D_ * C_];
    __shared__ float sb[C_];
    __shared__ float srow[4 * D_];
    for (int i = threadIdx.x; i < D_ * C_; i += 256) sW[i] = Wu[i];
    for (int i = threadIdx.x; i < C_; i += 256) sb[i] = bu[i];
    __syncthreads();

    for (int base = blockIdx.x * 4; base < nrows; base += gridDim.x * 4) {
        if (threadIdx.x < 4 * D_) {
            const int r = threadIdx.x >> 3, d = threadIdx.x & 7;
            const int row = base + r;
            srow[threadIdx.x] = (row < nrows) ? t2[(size_t)row * D_ + d] : 0.0f;
        }
        __syncthreads();
#pragma unroll
        for (int k = 0; k < 3; ++k) {
            const int task = threadIdx.x + k * 256;
            const int r  = task / 192;
            const int c4 = task - r * 192;
            const int row = base + r;
            if (row < nrows) {
                const float* td = &srow[r * D_];
                float4 o = *(const float4*)&sb[c4 * 4];
#pragma unroll
                for (int d = 0; d < D_; ++d) {
                    const float4 w = *(const float4*)&sW[d * C_ + c4 * 4];
                    const float tv = td[d];
                    o.x += tv * w.x; o.y += tv * w.y;
                    o.z += tv * w.z; o.w += tv * w.w;
                }
                *(float4*)&out[(size_t)row * C_ + (size_t)c4 * 4] = o;
            }
        }
        __syncthreads();
    }
}

extern "C" void kernel_launch(void* const* d_in, const int* in_sizes, int n_in,
                              void* d_out, int out_size, void* d_ws, size_t ws_size,
                              hipStream_t stream) {
    const float* x  = (const float*)d_in[0];
    const float* Wd = (const float*)d_in[1];
    const float* bd = (const float*)d_in[2];
    const float* Wc = (const float*)d_in[3];
    const float* bc = (const float*)d_in[4];
    const float* Wu = (const float*)d_in[5];
    const float* bu = (const float*)d_in[6];
    float* out = (float*)d_out;

    const int nrows = B_ * N_;                  // 65536
    float* t1 = (float*)d_ws;                   // [nrows][D_]  (2 MB)
    float* t2 = t1 + (size_t)nrows * D_;        // [nrows][D_]  (2 MB)

    // K1: 24 KB LDS -> 6 blocks/CU; 1536 blocks fills 256 CUs exactly.
    k_down<<<1536, 256, 0, stream>>>(x, Wd, bd, t1, nrows);
    // K2: 4 blocks per image
    k_conv<<<B_ * 4, 256, 0, stream>>>(t1, Wc, bc, t2);
    // K3: ~27 KB LDS -> 5 blocks/CU; 1280 blocks.
    k_up<<<1280, 256, 0, stream>>>(t2, Wu, bu, out, nrows);
}

// Round 2
// 117.148 us; speedup vs baseline: 1.6854x; 1.6854x over previous
//
#include <hip/hip_runtime.h>

// Problem dims (fixed by setup_inputs): x [B,N,C], adapter dim D, patch grid HxH
#define B_  64
#define N_  1024
#define H_  32
#define C_  768
#define D_  8

__device__ __forceinline__ float qgelu(float v) {
    // v * sigmoid(1.702 v) = v / (1 + exp(-1.702 v))
    return v / (1.0f + __expf(-1.702f * v));
}

// ---------------- Kernel 1: x_down = quick_gelu(x @ Wd + bd) ----------------
// One wave per row. Weight slice lives in REGISTERS (24 float4/lane, filled
// from LDS once per wave); inner loop is 3 global b128 loads + 96 fmac +
// a 10-shuffle reduce. Lane l ends with the full dot for
// d(l) = 4*(l&1) + 2*((l>>1)&1) + ((l>>2)&1); lanes 0-7 store 8 dwords.
__global__ __launch_bounds__(256, 3) void k_down(
    const float* __restrict__ x, const float* __restrict__ Wd,
    const float* __restrict__ bd, float* __restrict__ t1, int nrows)
{
    __shared__ float sW[D_ * C_];   // transposed: sW[d*C_ + c] = Wd[c*D_ + d]
    for (int i = threadIdx.x; i < D_ * C_; i += 256) {
        int d = i / C_, c = i - d * C_;
        sW[i] = Wd[c * D_ + d];
    }
    __syncthreads();

    const int wid  = threadIdx.x >> 6;
    const int lane = threadIdx.x & 63;

    // Fill the per-lane register weight file (96 VGPRs) — one-time LDS cost.
    float4 w[3][D_];
#pragma unroll
    for (int k = 0; k < 3; ++k)
#pragma unroll
        for (int d = 0; d < D_; ++d)
            w[k][d] = *(const float4*)&sW[d * C_ + (lane + k * 64) * 4];

    // Output slot this lane will own after the reduce, and its bias.
    const int dl = 4 * (lane & 1) + 2 * ((lane >> 1) & 1) + ((lane >> 2) & 1);
    const float bias = bd[dl];

    const int nw = gridDim.x * 4;
    for (int row = blockIdx.x * 4 + wid; row < nrows; row += nw) {
        const float4* xr = (const float4*)(x + (size_t)row * C_);
        float acc[D_];
#pragma unroll
        for (int d = 0; d < D_; ++d) acc[d] = 0.0f;

#pragma unroll
        for (int k = 0; k < 3; ++k) {
            const float4 v = xr[lane + k * 64];
#pragma unroll
            for (int d = 0; d < D_; ++d) {
                acc[d] += v.x * w[k][d].x + v.y * w[k][d].y
                        + v.z * w[k][d].z + v.w * w[k][d].w;
            }
        }

        // ---- cross-lane reduce: 10 shuffles, d halved each of first 3 steps
        {
            const bool hi = lane & 1;
#pragma unroll
            for (int j = 0; j < 4; ++j) {
                const float a = acc[j], b = acc[j + 4];
                acc[j]     = hi ? b : a;
                acc[j + 4] = hi ? a : b;
            }
#pragma unroll
            for (int j = 0; j < 4; ++j)
                acc[j] += __shfl_xor(acc[j + 4], 1, 64);
        }
        {
            const bool hi = lane & 2;
#pragma unroll
            for (int j = 0; j < 2; ++j) {
                const float a = acc[j], b = acc[j + 2];
                acc[j]     = hi ? b : a;
                acc[j + 2] = hi ? a : b;
            }
#pragma unroll
            for (int j = 0; j < 2; ++j)
                acc[j] += __shfl_xor(acc[j + 2], 2, 64);
        }
        {
            const bool hi = lane & 4;
            const float a = acc[0], b = acc[1];
            acc[0] = hi ? b : a;
            acc[1] = hi ? a : b;
            acc[0] += __shfl_xor(acc[1], 4, 64);
        }
        acc[0] += __shfl_xor(acc[0], 8, 64);
        acc[0] += __shfl_xor(acc[0], 16, 64);
        acc[0] += __shfl_xor(acc[0], 32, 64);

        if (lane < D_)
            t1[(size_t)row * D_ + dl] = qgelu(acc[0] + bias);
    }
}

// ------------- Kernel 2: t2 = quick_gelu(conv3x3(t1) + bc) ------------------
// 4 blocks per image; each block computes an 8-row strip of the 32x32 grid.
// Strip + zero-padded halo (10 rows) staged in LDS. 1 pixel per thread.
__global__ __launch_bounds__(256, 4) void k_conv(
    const float* __restrict__ t1, const float* __restrict__ Wc,
    const float* __restrict__ bc, float* __restrict__ t2)
{
    __shared__ float sIn[10 * H_ * D_];     // 10 rows x 32 cols x 8 ch = 10 KB
    __shared__ float sWc[9 * D_ * D_];      // 2304 B, layout [kh][kw][ci][co]
    __shared__ float sbc[D_];

    const int img   = blockIdx.x >> 2;
    const int strip = blockIdx.x & 3;
    const int h0    = strip * 8;
    const float* in = t1 + (size_t)img * N_ * D_;

    // load 10 rows (h0-1 .. h0+8) with zero pad outside [0,32)
#pragma unroll
    for (int j = 0; j < 10; ++j) {
        const int i  = threadIdx.x + j * 256;   // i in [0, 2560)
        const int lr = i >> 8;                  // local row (32*8 = 256/row)
        const int rem = i & 255;
        const int g  = h0 - 1 + lr;
        sIn[i] = (g >= 0 && g < H_) ? in[(size_t)g * H_ * D_ + rem] : 0.0f;
    }
    for (int i = threadIdx.x; i < 9 * D_ * D_; i += 256) sWc[i] = Wc[i];
    if (threadIdx.x < D_) sbc[threadIdx.x] = bc[threadIdx.x];
    __syncthreads();

    const int lh = threadIdx.x >> 5;            // 0..7 strip row
    const int w  = threadIdx.x & 31;            // 0..31 col
    float acc[D_];
#pragma unroll
    for (int co = 0; co < D_; ++co) acc[co] = sbc[co];

#pragma unroll
    for (int kh = 0; kh < 3; ++kh) {
        const int lrow = lh + kh;               // rows are zero-padded in LDS
#pragma unroll
        for (int kw = 0; kw < 3; ++kw) {
            const int ww = w + kw - 1;
            if (ww < 0 || ww >= H_) continue;
            const float* ip = &sIn[(lrow * H_ + ww) * D_];
            const float* wp = &sWc[(kh * 3 + kw) * D_ * D_];
#pragma unroll
            for (int ci = 0; ci < D_; ++ci) {
                const float iv = ip[ci];
#pragma unroll
                for (int co = 0; co < D_; ++co)
                    acc[co] += iv * wp[ci * D_ + co];
            }
        }
    }
    float4 o0, o1;
    o0.x = qgelu(acc[0]); o0.y = qgelu(acc[1]);
    o0.z = qgelu(acc[2]); o0.w = qgelu(acc[3]);
    o1.x = qgelu(acc[4]); o1.y = qgelu(acc[5]);
    o1.z = qgelu(acc[6]); o1.w = qgelu(acc[7]);
    float* tp = t2 + ((size_t)img * N_ + (size_t)(h0 + lh) * H_ + w) * D_;
    *(float4*)tp       = o0;
    *(float4*)(tp + 4) = o1;
}

// ---------------- Kernel 3: out = t2 @ Wu + bu ------------------------------
// Wu is [D][C] row-major already. Stage it (24 KB) + bu in LDS. Each block
// iteration covers 4 rows; 4 rows x 192 float4 = 768 tasks = 256 thr x 3.
__global__ __launch_bounds__(256, 4) void k_up(
    const float* __restrict__ t2, const float* __restrict__ Wu,
    const float* __restrict__ bu, float* __restrict__ out, int nrows)
{
    __shared__ float sW[D_ * C_];
    __shared__ float sb[C_];
    __shared__ float srow[4 * D_];
    for (int i = threadIdx.x; i < D_ * C_; i += 256) sW[i] = Wu[i];
    for (int i = threadIdx.x; i < C_; i += 256) sb[i] = bu[i];
    __syncthreads();

    for (int base = blockIdx.x * 4; base < nrows; base += gridDim.x * 4) {
        if (threadIdx.x < 4 * D_) {
            const int r = threadIdx.x >> 3, d = threadIdx.x & 7;
            const int row = base + r;
            srow[threadIdx.x] = (row < nrows) ? t2[(size_t)row * D_ + d] : 0.0f;
        }
        __syncthreads();
#pragma unroll
        for (int k = 0; k < 3; ++k) {
            const int task = threadIdx.x + k * 256;
            const int r  = task / 192;
            const int c4 = task - r * 192;
            const int row = base + r;
            if (row < nrows) {
                const float* td = &srow[r * D_];
                float4 o = *(const float4*)&sb[c4 * 4];
#pragma unroll
                for (int d = 0; d < D_; ++d) {
                    const float4 w = *(const float4*)&sW[d * C_ + c4 * 4];
                    const float tv = td[d];
                    o.x += tv * w.x; o.y += tv * w.y;
                    o.z += tv * w.z; o.w += tv * w.w;
                }
                *(float4*)&out[(size_t)row * C_ + (size_t)c4 * 4] = o;
            }
        }
        __syncthreads();
    }
}

extern "C" void kernel_launch(void* const* d_in, const int* in_sizes, int n_in,
                              void* d_out, int out_size, void* d_ws, size_t ws_size,
                              hipStream_t stream) {
    const float* x  = (const float*)d_in[0];
    const float* Wd = (const float*)d_in[1];
    const float* bd = (const float*)d_in[2];
    const float* Wc = (const float*)d_in[3];
    const float* bc = (const float*)d_in[4];
    const float* Wu = (const float*)d_in[5];
    const float* bu = (const float*)d_in[6];
    float* out = (float*)d_out;

    const int nrows = B_ * N_;                  // 65536
    float* t1 = (float*)d_ws;                   // [nrows][D_]  (2 MB)
    float* t2 = t1 + (size_t)nrows * D_;        // [nrows][D_]  (2 MB)

    // K1: VGPR-heavy (weights in registers) -> ~3 waves/SIMD; 768 blocks
    // = 3 blocks/CU resident, grid-stride over 65536 rows.
    k_down<<<768, 256, 0, stream>>>(x, Wd, bd, t1, nrows);
    // K2: 4 blocks per image
    k_conv<<<B_ * 4, 256, 0, stream>>>(t1, Wc, bc, t2);
    // K3: ~27 KB LDS -> 5 blocks/CU; 1280 blocks.
    k_up<<<1280, 256, 0, stream>>>(t2, Wu, bu, out, nrows);
}